// Round 15
// baseline (139.669 us; speedup 1.0000x reference)
//
#include <hip/hip_runtime.h>
#include <hip/hip_bf16.h>
#include <stdint.h>

#define NB    32
#define CIN   128
#define HIN   56
#define HW    (HIN*HIN)     // 3136
#define OCH   256
#define OHW   54
#define SPB   (OHW*OHW)     // 2916
#define KSZ   (CIN*9)       // 1152 = GEMM K
#define BM    256           // oc rows per block (= OCH)
#define BN    128           // flattened (n,sp) cols; 93312/128 = 729 exact
#define BK    32
#define NKS   (KSZ/BK)      // 36 K-tiles (even)
#define TOTC  (NB*SPB)      // 93312
#define NT    729

typedef __attribute__((ext_vector_type(8))) short bf16x8;
typedef __attribute__((ext_vector_type(4))) float f32x4;

// ---- pre-pass 1: x NCHW f32 -> NHWC bf16 ----
__global__ void xpose_cast(const float* __restrict__ x, __hip_bfloat16* __restrict__ xt) {
    __shared__ float tile[32][33];
    const int hw0 = blockIdx.x * 32;
    const int c0  = blockIdx.y * 32;
    const int n   = blockIdx.z;
    const int tx = threadIdx.x, ty = threadIdx.y;
    const float* xp = x + ((size_t)n*CIN + c0)*HW + hw0;
    #pragma unroll
    for (int i = ty; i < 32; i += 8)
        tile[i][tx] = xp[(size_t)i*HW + tx];
    __syncthreads();
    const int t = ty*32 + tx;
    const int hwl = t >> 3, q = t & 7;
    ushort4 v;
    v.x = __bfloat16_as_ushort(__float2bfloat16(tile[q*4+0][hwl]));
    v.y = __bfloat16_as_ushort(__float2bfloat16(tile[q*4+1][hwl]));
    v.z = __bfloat16_as_ushort(__float2bfloat16(tile[q*4+2][hwl]));
    v.w = __bfloat16_as_ushort(__float2bfloat16(tile[q*4+3][hwl]));
    __hip_bfloat16* op = xt + ((size_t)n*HW + hw0 + hwl)*CIN + c0 + q*4;
    *(ushort4*)op = v;
}

// ---- pre-pass 2: weight OIHW f32 -> [oc][(kh*3+kw)*128+ic] bf16 ----
__global__ void wcast(const float* __restrict__ w, __hip_bfloat16* __restrict__ wt) {
    int tid = blockIdx.x*256 + threadIdx.x;
    if (tid >= OCH*KSZ) return;
    int oc = tid / KSZ, r = tid % KSZ;
    int pos = r >> 7, ic = r & 127;
    wt[tid] = __float2bfloat16(w[((size_t)(oc*CIN + ic))*9 + pos]);
}

// ---- main: implicit-GEMM bf16 MFMA conv, A-from-global / B-reg-staged-LDS ----
// grid (729), block 256 = 4 waves (2M x 2N), per-wave 128x64 (acc 8x4).
// A (weights, 576KB L2-resident, panel 16KB L1-resident): plain global->reg,
// aE/aO rotation so A(t+1)'s latency hides under MFMA(t).
// B: global->reg->ds_write, double buffer 2x8KB. NO gl_lds, NO raw barriers,
// NO asm waitcnt — all ordering via compiler-tracked ops + __syncthreads()
// (rounds 13/14's gl_lds+asm mix diverged on replays; this is textbook-safe).
// LDS traffic per block-tile: 24KB vs round-11's 72KB (measured 88 B/cyc wall).
__global__ __launch_bounds__(256, 2)
void conv_mfma(const __hip_bfloat16* __restrict__ xt,
               const __hip_bfloat16* __restrict__ wt,
               const float* __restrict__ bias,
               float* __restrict__ out) {
    __shared__ uint4 smem[2112];   // B dbuf: 2x512 granules (16KB); epilogue 33792B

    const int t = threadIdx.x;
    // bijective XCD swizzle: nwg=729 = 8*91+1 -> q=91, r=1
    const int orig = blockIdx.x;
    const int xcd = orig & 7;
    const int tile = (xcd < 1 ? xcd*92 : 92 + (xcd-1)*91) + (orig >> 3);

    const int lane = t & 63, wid = t >> 6;
    const int wm = wid >> 1, wn = wid & 1;     // per-wave 128 rows x 64 cols
    const int lr = lane & 15, lq = lane >> 4;

    // A per-lane element indices (SGPR base + 32-bit offset form)
    int aidx[8];
    #pragma unroll
    for (int mi = 0; mi < 8; ++mi)
        aidx[mi] = (wm*128 + mi*16 + lr)*KSZ + lq*8;

    // B staging sources (512 granules, 2/thread); slot j holds k-chunk j^((col>>1)&3)
    const __hip_bfloat16* bsrc0;
    const __hip_bfloat16* bsrc1;
    {
        int q0 = t, c0i = q0 >> 2, j0 = q0 & 3;
        int l0 = j0 ^ ((c0i >> 1) & 3);
        int cg0 = tile*BN + c0i;
        int n0 = cg0 / SPB, r0 = cg0 - n0*SPB;
        bsrc0 = xt + ((size_t)(n0*HIN + r0/OHW)*HIN + r0%OHW)*CIN + l0*8;
        int q1 = 256 + t, c1i = q1 >> 2, j1 = q1 & 3;
        int l1 = j1 ^ ((c1i >> 1) & 3);
        int cg1 = tile*BN + c1i;
        int n1 = cg1 / SPB, r1 = cg1 - n1*SPB;
        bsrc1 = xt + ((size_t)(n1*HIN + r1/OHW)*HIN + r1%OHW)*CIN + l1*8;
    }

    // B read offsets (granule units within a buffer)
    int bo[4];
    #pragma unroll
    for (int ni = 0; ni < 4; ++ni) {
        int cb = wn*64 + ni*16 + lr;
        bo[ni] = cb*4 + (lq ^ ((cb >> 1) & 3));
    }

    f32x4 acc[8][4];
    #pragma unroll
    for (int i = 0; i < 8; ++i)
        #pragma unroll
        for (int j = 0; j < 4; ++j)
            acc[i][j] = (f32x4){0.f, 0.f, 0.f, 0.f};

    #define MFMA_BF16 __builtin_amdgcn_mfma_f32_16x16x32_bf16
    #define BOFF(KS) (((KS) >> 2) / 3 * HIN + ((KS) >> 2) % 3) * CIN + ((KS) & 3)*32
    #define LOADB(KS) do { \
        const int _o = BOFF(KS); \
        s0 = *(const uint4*)(bsrc0 + _o); \
        s1 = *(const uint4*)(bsrc1 + _o); } while (0)
    #define WRITEB(KS) do { \
        uint4* _d = smem + ((KS) & 1)*512; \
        _d[t] = s0; _d[256 + t] = s1; } while (0)
    #define LDA(ARR, KS) \
        _Pragma("unroll") for (int mi = 0; mi < 8; ++mi) \
            ARR[mi] = *(const bf16x8*)(wt + aidx[mi] + (KS)*BK);
    #define MFMA32(ACUR) \
        __builtin_amdgcn_s_setprio(1); \
        _Pragma("unroll") for (int mi = 0; mi < 8; ++mi) \
            _Pragma("unroll") for (int ni = 0; ni < 4; ++ni) \
                acc[mi][ni] = MFMA_BF16(ACUR[mi], bb[ni], acc[mi][ni], 0, 0, 0); \
        __builtin_amdgcn_s_setprio(0);

    bf16x8 aE[8], aO[8];
    uint4 s0, s1;

    // prologue: B(0) -> buf0; B(1) -> regs; A(0) -> aE; publish buf0
    LOADB(0);
    WRITEB(0);
    LOADB(1);
    LDA(aE, 0)
    __syncthreads();

    for (int ks = 0; ks < NKS; ks += 2) {
        // ---- even half: tile ks (buf0, aE) ----
        {
            WRITEB(ks + 1);                    // buf1: its readers (tile ks-1) done at prev barrier
            if (ks + 2 < NKS) LOADB(ks + 2);
            LDA(aO, ks + 1)                    // ks+1 <= 35 always
            bf16x8 bb[4];
            const uint4* bp = smem + 0;
            #pragma unroll
            for (int ni = 0; ni < 4; ++ni) bb[ni] = *(const bf16x8*)&bp[bo[ni]];
            MFMA32(aE)
            __syncthreads();                   // publish buf1; all buf0 reads done
        }
        // ---- odd half: tile ks+1 (buf1, aO) ----
        {
            if (ks + 2 < NKS) WRITEB(ks + 2);  // buf0: readers (tile ks) done at prev barrier
            if (ks + 3 < NKS) LOADB(ks + 3);
            if (ks + 2 < NKS) { LDA(aE, ks + 2) }
            bf16x8 bb[4];
            const uint4* bp = smem + 512;
            #pragma unroll
            for (int ni = 0; ni < 4; ++ni) bb[ni] = *(const bf16x8*)&bp[bo[ni]];
            MFMA32(aO)
            __syncthreads();                   // publish buf0; all buf1 reads done
        }
    }

    // --- epilogue: LDS restage [64][132] (2-way free), coalesced float4 stores ---
    float (*eps)[132] = (float (*)[132])smem;
    const int cl4 = (t & 31) * 4;                 // 0..124
    const int rsub = t >> 5;                      // 0..7
    const int colg = tile*BN + cl4;
    const int nn = colg / SPB;
    const int sp = colg - nn*SPB;                 // SPB%4==0 -> no straddle
    #pragma unroll
    for (int h = 0; h < 4; ++h) {
        if (wm == (h >> 1)) {
            const int mib = (h & 1) * 4;
            #pragma unroll
            for (int ii = 0; ii < 4; ++ii) {
                int rl = ii*16 + lq*4;
                #pragma unroll
                for (int ni = 0; ni < 4; ++ni) {
                    int cl = wn*64 + ni*16 + lr;
                    #pragma unroll
                    for (int r = 0; r < 4; ++r)
                        eps[rl + r][cl] = acc[mib + ii][ni][r];
                }
            }
        }
        __syncthreads();
        {
            #pragma unroll
            for (int pass = 0; pass < 8; ++pass) {
                int rl = pass*8 + rsub;
                int rg = h*64 + rl;
                f32x4 v = *(f32x4*)&eps[rl][cl4];
                v = v + bias[rg];
                *(f32x4*)&out[((size_t)nn*OCH + rg)*SPB + sp] = v;
            }
        }
        __syncthreads();
    }
}

// ---- fallback: direct fp32 conv ----
__global__ void conv_naive(const float* __restrict__ x, const float* __restrict__ w,
                           const float* __restrict__ bias, float* __restrict__ out) {
    size_t tid = (size_t)blockIdx.x*256 + threadIdx.x;
    const size_t total = (size_t)NB*OCH*SPB;
    if (tid >= total) return;
    int col = (int)(tid % SPB);
    int oc  = (int)((tid / SPB) % OCH);
    int n   = (int)(tid / ((size_t)SPB*OCH));
    int oh = col / OHW, ow = col % OHW;
    float s = bias[oc];
    for (int ic = 0; ic < CIN; ++ic)
        #pragma unroll
        for (int kh = 0; kh < 3; ++kh)
            #pragma unroll
            for (int kw = 0; kw < 3; ++kw)
                s += x[((size_t)(n*CIN+ic)*HIN + oh+kh)*HIN + ow+kw]
                   * w[((size_t)(oc*CIN+ic)*3 + kh)*3 + kw];
    out[tid] = s;
}

extern "C" void kernel_launch(void* const* d_in, const int* in_sizes, int n_in,
                              void* d_out, int out_size, void* d_ws, size_t ws_size,
                              hipStream_t stream) {
    const float* x    = (const float*)d_in[0];
    const float* w    = (const float*)d_in[1];
    const float* bias = (const float*)d_in[2];
    float* out = (float*)d_out;

    const size_t xt_bytes = (size_t)NB*HW*CIN*sizeof(__hip_bfloat16);
    const size_t wt_bytes = (size_t)OCH*KSZ*sizeof(__hip_bfloat16);

    if (ws_size >= xt_bytes + wt_bytes) {
        __hip_bfloat16* xt  = (__hip_bfloat16*)d_ws;
        __hip_bfloat16* wtp = (__hip_bfloat16*)((char*)d_ws + xt_bytes);
        hipLaunchKernelGGL(xpose_cast, dim3(HW/32, CIN/32, NB), dim3(32, 8), 0, stream, x, xt);
        hipLaunchKernelGGL(wcast, dim3((OCH*KSZ + 255)/256), dim3(256), 0, stream, w, wtp);
        hipLaunchKernelGGL(conv_mfma, dim3(NT), dim3(256), 0, stream, xt, wtp, bias, out);
    } else {
        size_t total = (size_t)NB*OCH*SPB;
        hipLaunchKernelGGL(conv_naive, dim3((unsigned)((total + 255)/256)), dim3(256), 0, stream,
                           x, w, bias, out);
    }
}

// Round 16
// 97.919 us; speedup vs baseline: 1.4264x; 1.4264x over previous
//
#include <hip/hip_runtime.h>
#include <hip/hip_bf16.h>
#include <stdint.h>

#define NB    32
#define CIN   128
#define HIN   56
#define HW    (HIN*HIN)     // 3136
#define OCH   256
#define OHW   54
#define SPB   (OHW*OHW)     // 2916
#define KSZ   (CIN*9)       // 1152 = GEMM K
#define BM    256           // oc rows per block (= OCH)
#define BN    128           // flattened (n,sp) cols; 93312/128 = 729 exact
#define BK    32
#define NKS   (KSZ/BK)      // 36 K-tiles (even)
#define TOTC  (NB*SPB)      // 93312
#define NT    729
#define GRAN  1536          // (BM+BN)*4 granules (16B) per buffer = 24KB

typedef __attribute__((ext_vector_type(8))) short bf16x8;
typedef __attribute__((ext_vector_type(4))) float f32x4;

typedef __attribute__((address_space(1))) const uint32_t g_u32;
typedef __attribute__((address_space(3))) uint32_t l_u32;
static __device__ __forceinline__ void gl_lds16(const void* g, void* l) {
    __builtin_amdgcn_global_load_lds((g_u32*)g, (l_u32*)l, 16, 0, 0);
}

// ---- pre-pass 1: x NCHW f32 -> NHWC bf16 ----
__global__ void xpose_cast(const float* __restrict__ x, __hip_bfloat16* __restrict__ xt) {
    __shared__ float tile[32][33];
    const int hw0 = blockIdx.x * 32;
    const int c0  = blockIdx.y * 32;
    const int n   = blockIdx.z;
    const int tx = threadIdx.x, ty = threadIdx.y;
    const float* xp = x + ((size_t)n*CIN + c0)*HW + hw0;
    #pragma unroll
    for (int i = ty; i < 32; i += 8)
        tile[i][tx] = xp[(size_t)i*HW + tx];
    __syncthreads();
    const int t = ty*32 + tx;
    const int hwl = t >> 3, q = t & 7;
    ushort4 v;
    v.x = __bfloat16_as_ushort(__float2bfloat16(tile[q*4+0][hwl]));
    v.y = __bfloat16_as_ushort(__float2bfloat16(tile[q*4+1][hwl]));
    v.z = __bfloat16_as_ushort(__float2bfloat16(tile[q*4+2][hwl]));
    v.w = __bfloat16_as_ushort(__float2bfloat16(tile[q*4+3][hwl]));
    __hip_bfloat16* op = xt + ((size_t)n*HW + hw0 + hwl)*CIN + c0 + q*4;
    *(ushort4*)op = v;
}

// ---- pre-pass 2: weight OIHW f32 -> [oc][(kh*3+kw)*128+ic] bf16 ----
__global__ void wcast(const float* __restrict__ w, __hip_bfloat16* __restrict__ wt) {
    int tid = blockIdx.x*256 + threadIdx.x;
    if (tid >= OCH*KSZ) return;
    int oc = tid / KSZ, r = tid % KSZ;
    int pos = r >> 7, ic = r & 127;
    wt[tid] = __float2bfloat16(w[((size_t)(oc*CIN + ic))*9 + pos]);
}

// ---- main: implicit-GEMM bf16 MFMA conv, cross-tile fragment rotation ----
// grid (729), block 256 = 4 waves (2M x 2N), per-wave 128x64 (acc 8x4).
// BK=32, triple buffer 72KB (2 blocks/CU). Per tile t:
//   stage(t+2) -> MFMA1(t) -> ds_read frags(t+1) -> MFMA2(t)
//   -> s_waitcnt vmcnt(0) lgkmcnt(0) -> s_barrier
// Reads of buf[t+1] are legal: all waves drained stage(t+1) before the
// end-of-(t-1) barrier. Stage(t+2) overwrites a slot whose last reads
// (frags(t-1), during tile t-2) retired two barriers earlier. Drain at tile
// end is ~760 cyc after the stage issue (MFMA1+reads+MFMA2) -> L2/L3 covered
// (r12's failure was draining loads issued only a half-tile prior).
__global__ __launch_bounds__(256, 2)
void conv_mfma(const __hip_bfloat16* __restrict__ xt,
               const __hip_bfloat16* __restrict__ wt,
               const float* __restrict__ bias,
               float* __restrict__ out) {
    __shared__ uint4 smem[3*GRAN];   // 73728 B

    const int t = threadIdx.x;
    // bijective XCD swizzle: nwg=729 = 8*91+1 -> q=91, r=1
    const int orig = blockIdx.x;
    const int xcd = orig & 7;
    const int tile = (xcd < 1 ? xcd*92 : 92 + (xcd-1)*91) + (orig >> 3);

    const int lane = t & 63, wid = t >> 6;
    const int wm = wid >> 1, wn = wid & 1;     // per-wave 128 rows x 64 cols
    const int lr = lane & 15, lq = lane >> 4;

    // staging sources (slot j holds logical k-chunk j ^ ((row>>1)&3); 2-way free)
    const __hip_bfloat16* asrc[4];
    #pragma unroll
    for (int i = 0; i < 4; ++i) {
        int q = i*256 + t;
        int row = q >> 2, j = q & 3;
        int ls = j ^ ((row >> 1) & 3);
        asrc[i] = wt + (size_t)row*KSZ + ls*8;
    }
    const __hip_bfloat16* bsrc[2];
    #pragma unroll
    for (int i = 0; i < 2; ++i) {
        int q = i*256 + t;
        int col = q >> 2, j = q & 3;
        int ls = j ^ ((col >> 1) & 3);
        int colg = tile*BN + col;              // exact tiling
        int n = colg / SPB, rem = colg - n*SPB;
        int oh = rem / OHW, ow = rem - oh*OHW;
        bsrc[i] = xt + ((size_t)(n*HIN + oh)*HIN + ow)*CIN + ls*8;
    }

    auto issueT = [&](uint4* dst, int ks) {    // 6 gl_lds: tile ks -> dst buffer
        const int aoff = ks*BK;
        const int pos = ks >> 2;
        const int kh = pos / 3, kw = pos - kh*3;
        const int boff = (kh*HIN + kw)*CIN + (ks & 3)*32;
        #pragma unroll
        for (int i = 0; i < 4; ++i) gl_lds16(asrc[i] + aoff, dst + i*256 + t);
        #pragma unroll
        for (int i = 0; i < 2; ++i) gl_lds16(bsrc[i] + boff, dst + 1024 + i*256 + t);
    };

    // per-lane read offsets (granule units)
    int ao[8], bo[4];
    #pragma unroll
    for (int mi = 0; mi < 8; ++mi) {
        int ra = wm*128 + mi*16 + lr;
        ao[mi] = ra*4 + (lq ^ ((ra >> 1) & 3));
    }
    #pragma unroll
    for (int ni = 0; ni < 4; ++ni) {
        int cb = wn*64 + ni*16 + lr;
        bo[ni] = 1024 + cb*4 + (lq ^ ((cb >> 1) & 3));
    }

    f32x4 acc[8][4];
    #pragma unroll
    for (int i = 0; i < 8; ++i)
        #pragma unroll
        for (int j = 0; j < 4; ++j)
            acc[i][j] = (f32x4){0.f, 0.f, 0.f, 0.f};

    #define MFMA_BF16 __builtin_amdgcn_mfma_f32_16x16x32_bf16
    #define RDSET(AA, AB, BB, P) \
        _Pragma("unroll") for (int mi = 0; mi < 4; ++mi) AA[mi] = *(bf16x8*)&(P)[ao[mi]]; \
        _Pragma("unroll") for (int ni = 0; ni < 4; ++ni) BB[ni] = *(bf16x8*)&(P)[bo[ni]]; \
        _Pragma("unroll") for (int mi = 0; mi < 4; ++mi) AB[mi] = *(bf16x8*)&(P)[ao[4 + mi]];
    #define MFMA16(AARR, BARR, MIB) \
        __builtin_amdgcn_s_setprio(1); \
        _Pragma("unroll") for (int mi = 0; mi < 4; ++mi) \
            _Pragma("unroll") for (int ni = 0; ni < 4; ++ni) \
                acc[(MIB)+mi][ni] = MFMA_BF16(AARR[mi], BARR[ni], acc[(MIB)+mi][ni], 0, 0, 0); \
        __builtin_amdgcn_s_setprio(0);
    #define SCHEDB __builtin_amdgcn_sched_barrier(0)
    #define DRAIN_BARRIER() \
        asm volatile("s_waitcnt vmcnt(0) lgkmcnt(0)" ::: "memory"); \
        __builtin_amdgcn_s_barrier(); \
        SCHEDB;

    uint4 *pR = smem, *pN = smem + GRAN, *pS = smem + 2*GRAN;
    bf16x8 aaE[4], abE[4], bbE[4];   // frags for even tiles
    bf16x8 aaO[4], abO[4], bbO[4];   // frags for odd tiles

    // prologue: stage(0), stage(1); drain; read frags(0) -> E
    issueT(pR, 0); issueT(pN, 1);
    DRAIN_BARRIER()
    RDSET(aaE, abE, bbE, pR)
    asm volatile("s_waitcnt lgkmcnt(0)" ::: "memory");
    SCHEDB;

    for (int ks = 0; ks < NKS; ks += 2) {
        // ---- even tile ks: consume E; read frags(ks+1) -> O from pN ----
        if (ks + 2 < NKS) issueT(pS, ks + 2);
        MFMA16(aaE, bbE, 0)
        RDSET(aaO, abO, bbO, pN)       // buf[ks+1] certified at prior barrier
        SCHEDB;                        // pin reads above MFMA2 (issue early)
        MFMA16(abE, bbE, 4)
        DRAIN_BARRIER()                // retires stage(ks+2) (issued ~760cyc ago)
        { uint4* t0 = pR; pR = pN; pN = pS; pS = t0; }

        // ---- odd tile ks+1: consume O; read frags(ks+2) -> E from pN ----
        if (ks + 3 < NKS) issueT(pS, ks + 3);
        MFMA16(aaO, bbO, 0)
        if (ks + 2 < NKS) { RDSET(aaE, abE, bbE, pN) }
        SCHEDB;
        MFMA16(abO, bbO, 4)
        if (ks + 2 < NKS) {
            DRAIN_BARRIER()
        } else {
            asm volatile("s_waitcnt lgkmcnt(0)" ::: "memory");
        }
        { uint4* t0 = pR; pR = pN; pN = pS; pS = t0; }
    }

    __syncthreads();

    // --- epilogue: LDS restage [64][132] (2-way free), coalesced float4 stores ---
    float (*eps)[132] = (float (*)[132])smem;
    const int cl4 = (t & 31) * 4;                 // 0..124
    const int rsub = t >> 5;                      // 0..7
    const int colg = tile*BN + cl4;
    const int nn = colg / SPB;
    const int sp = colg - nn*SPB;                 // SPB%4==0 -> no straddle
    #pragma unroll
    for (int h = 0; h < 4; ++h) {
        if (wm == (h >> 1)) {
            const int mib = (h & 1) * 4;
            #pragma unroll
            for (int ii = 0; ii < 4; ++ii) {
                int rl = ii*16 + lq*4;
                #pragma unroll
                for (int ni = 0; ni < 4; ++ni) {
                    int cl = wn*64 + ni*16 + lr;
                    #pragma unroll
                    for (int r = 0; r < 4; ++r)
                        eps[rl + r][cl] = acc[mib + ii][ni][r];
                }
            }
        }
        __syncthreads();
        {
            #pragma unroll
            for (int pass = 0; pass < 8; ++pass) {
                int rl = pass*8 + rsub;
                int rg = h*64 + rl;
                f32x4 v = *(f32x4*)&eps[rl][cl4];
                v = v + bias[rg];
                *(f32x4*)&out[((size_t)nn*OCH + rg)*SPB + sp] = v;
            }
        }
        __syncthreads();
    }
}

// ---- fallback: direct fp32 conv ----
__global__ void conv_naive(const float* __restrict__ x, const float* __restrict__ w,
                           const float* __restrict__ bias, float* __restrict__ out) {
    size_t tid = (size_t)blockIdx.x*256 + threadIdx.x;
    const size_t total = (size_t)NB*OCH*SPB;
    if (tid >= total) return;
    int col = (int)(tid % SPB);
    int oc  = (int)((tid / SPB) % OCH);
    int n   = (int)(tid / ((size_t)SPB*OCH));
    int oh = col / OHW, ow = col % OHW;
    float s = bias[oc];
    for (int ic = 0; ic < CIN; ++ic)
        #pragma unroll
        for (int kh = 0; kh < 3; ++kh)
            #pragma unroll
            for (int kw = 0; kw < 3; ++kw)
                s += x[((size_t)(n*CIN+ic)*HIN + oh+kh)*HIN + ow+kw]
                   * w[((size_t)(oc*CIN+ic)*3 + kh)*3 + kw];
    out[tid] = s;
}

extern "C" void kernel_launch(void* const* d_in, const int* in_sizes, int n_in,
                              void* d_out, int out_size, void* d_ws, size_t ws_size,
                              hipStream_t stream) {
    const float* x    = (const float*)d_in[0];
    const float* w    = (const float*)d_in[1];
    const float* bias = (const float*)d_in[2];
    float* out = (float*)d_out;

    const size_t xt_bytes = (size_t)NB*HW*CIN*sizeof(__hip_bfloat16);
    const size_t wt_bytes = (size_t)OCH*KSZ*sizeof(__hip_bfloat16);

    if (ws_size >= xt_bytes + wt_bytes) {
        __hip_bfloat16* xt  = (__hip_bfloat16*)d_ws;
        __hip_bfloat16* wtp = (__hip_bfloat16*)((char*)d_ws + xt_bytes);
        hipLaunchKernelGGL(xpose_cast, dim3(HW/32, CIN/32, NB), dim3(32, 8), 0, stream, x, xt);
        hipLaunchKernelGGL(wcast, dim3((OCH*KSZ + 255)/256), dim3(256), 0, stream, w, wtp);
        hipLaunchKernelGGL(conv_mfma, dim3(NT), dim3(256), 0, stream, xt, wtp, bias, out);
    } else {
        size_t total = (size_t)NB*OCH*SPB;
        hipLaunchKernelGGL(conv_naive, dim3((unsigned)((total + 255)/256)), dim3(256), 0, stream,
                           x, w, bias, out);
    }
}

// Round 17
// 80.236 us; speedup vs baseline: 1.7407x; 1.2204x over previous
//
#include <hip/hip_runtime.h>
#include <hip/hip_bf16.h>
#include <stdint.h>

#define NB    32
#define CIN   128
#define HIN   56
#define HW    (HIN*HIN)     // 3136
#define OCH   256
#define OHW   54
#define SPB   (OHW*OHW)     // 2916
#define KSZ   (CIN*9)       // 1152 = GEMM K
#define BM    256           // oc rows per block (= OCH)
#define BN    192           // flattened (n,sp) cols; 93312/192 = 486 exact
#define BK    64
#define NKS   (KSZ/BK)      // 18 K-tiles
#define TOTC  (NB*SPB)      // 93312
#define NT    486
#define GRAN  ((BM+BN)*8)   // 3584 granules (16B) per buffer = 56KB

#define XPB   (98*4*NB)     // 12544 xpose blocks
#define WCB   ((OCH*KSZ)/256) // 1152 wcast blocks

typedef __attribute__((ext_vector_type(8))) short bf16x8;
typedef __attribute__((ext_vector_type(4))) float f32x4;

typedef __attribute__((address_space(1))) const uint32_t g_u32;
typedef __attribute__((address_space(3))) uint32_t l_u32;
static __device__ __forceinline__ void gl_lds16(const void* g, void* l) {
    __builtin_amdgcn_global_load_lds((g_u32*)g, (l_u32*)l, 16, 0, 0);
}

// ---- fused pre-pass: x NCHW f32 -> NHWC bf16  +  w OIHW f32 -> packed bf16 ----
// grid.x = XPB + WCB, block 256. Blocks are independent; partition by blockIdx.
__global__ void prep(const float* __restrict__ x, __hip_bfloat16* __restrict__ xt,
                     const float* __restrict__ w, __hip_bfloat16* __restrict__ wt) {
    __shared__ float tile[32][33];
    const int bid = blockIdx.x;
    const int t = threadIdx.x;
    if (bid < XPB) {
        const int hwb = bid % 98;
        const int cb  = (bid / 98) & 3;
        const int n   = bid / 392;
        const int hw0 = hwb * 32, c0 = cb * 32;
        const int tx = t & 31, ty = t >> 5;
        const float* xp = x + ((size_t)n*CIN + c0)*HW + hw0;
        #pragma unroll
        for (int i = ty; i < 32; i += 8)
            tile[i][tx] = xp[(size_t)i*HW + tx];
        __syncthreads();
        const int hwl = t >> 3, q = t & 7;
        ushort4 v;
        v.x = __bfloat16_as_ushort(__float2bfloat16(tile[q*4+0][hwl]));
        v.y = __bfloat16_as_ushort(__float2bfloat16(tile[q*4+1][hwl]));
        v.z = __bfloat16_as_ushort(__float2bfloat16(tile[q*4+2][hwl]));
        v.w = __bfloat16_as_ushort(__float2bfloat16(tile[q*4+3][hwl]));
        __hip_bfloat16* op = xt + ((size_t)n*HW + hw0 + hwl)*CIN + c0 + q*4;
        *(ushort4*)op = v;
    } else {
        int tid = (bid - XPB)*256 + t;           // < OCH*KSZ exactly
        int oc = tid / KSZ, r = tid % KSZ;
        int pos = r >> 7, ic = r & 127;
        wt[tid] = __float2bfloat16(w[((size_t)(oc*CIN + ic))*9 + pos]);
    }
}

// ---- main: implicit-GEMM bf16 MFMA conv (round-9 config: best measured) ----
// grid (486), block 512 = 8 waves (2M x 4N), per-wave 128x48.
// BK=64, DOUBLE buffer (2 x 56KB), ONE barrier + vmcnt(0)-certify per K-tile
// (stages issued ~3/4 tile before the certify -> latency fully covered);
// free-running waves inside the tile with own-wave counted lgkm splits.
// LDS layout per buffer: [A rows 0..255 | B rows 0..191] x 8 granules/row,
// slot j of row holds logical k-chunk j ^ (row&7)  (bank-perfect: 8 words/bank).
__global__ __launch_bounds__(512, 2)
void conv_mfma(const __hip_bfloat16* __restrict__ xt,
               const __hip_bfloat16* __restrict__ wt,
               const float* __restrict__ bias,
               float* __restrict__ out) {
    __shared__ uint4 smem[2*GRAN];   // 114688 B

    const int t = threadIdx.x;
    // bijective XCD swizzle: nwg=486 = 8*60+6 -> q=60, r=6
    const int orig = blockIdx.x;
    const int xcd = orig & 7;
    const int tile = (xcd < 6 ? xcd*61 : 6*61 + (xcd-6)*60) + (orig >> 3);

    const int lane = t & 63, wid = t >> 6;
    const int wm = wid >> 2, wn = wid & 3;     // per-wave 128 rows x 48 cols
    const int lr = lane & 15, lq = lane >> 4;

    // staging sources: A granules q = i*512+t (i<4); B q = i*512+t (i<3)
    const __hip_bfloat16* aptr[4];
    #pragma unroll
    for (int i = 0; i < 4; ++i) {
        int q = i*512 + t;
        int row = q >> 3, j = q & 7;
        int ls = j ^ (row & 7);
        aptr[i] = wt + (size_t)row*KSZ + ls*8;
    }
    const __hip_bfloat16* bptr[3];
    #pragma unroll
    for (int i = 0; i < 3; ++i) {
        int q = i*512 + t;
        int row = q >> 3, j = q & 7;
        int ls = j ^ (row & 7);
        int colg = tile*BN + row;              // exact tiling: always < TOTC
        int n = colg / SPB, rem = colg - n*SPB;
        int oh = rem / OHW, ow = rem - oh*OHW;
        bptr[i] = xt + ((size_t)(n*HIN + oh)*HIN + ow)*CIN + ls*8;
    }

    auto issueT = [&](int ks) {      // 7 gl_lds: full tile ks -> buf[ks&1]
        uint4* dst = smem + (ks & 1)*GRAN;
        const int aoff = ks*BK;
        const int pos = ks >> 1;
        const int kh = pos / 3, kw = pos - kh*3;
        const int boff = (kh*HIN + kw)*CIN + (ks & 1)*64;
        #pragma unroll
        for (int i = 0; i < 4; ++i) gl_lds16(aptr[i] + aoff, dst + i*512 + t);
        #pragma unroll
        for (int i = 0; i < 3; ++i) gl_lds16(bptr[i] + boff, dst + 2048 + i*512 + t);
    };

    // per-lane read offsets (granule units), kk=0; kk=1 is ^4 (flips slot bit 2)
    int ao[8], bo[3];
    #pragma unroll
    for (int mi = 0; mi < 8; ++mi) {
        int ra = wm*128 + mi*16 + lr;
        ao[mi] = ra*8 + (lq ^ (ra & 7));
    }
    #pragma unroll
    for (int ni = 0; ni < 3; ++ni) {
        int rb = wn*48 + ni*16 + lr;
        bo[ni] = 2048 + rb*8 + (lq ^ (rb & 7));
    }

    f32x4 acc[8][3];
    #pragma unroll
    for (int i = 0; i < 8; ++i)
        #pragma unroll
        for (int j = 0; j < 3; ++j)
            acc[i][j] = (f32x4){0.f, 0.f, 0.f, 0.f};

    #define MFMA_BF16 __builtin_amdgcn_mfma_f32_16x16x32_bf16
    #define MFMA12(AARR, MIB, BARR) \
        __builtin_amdgcn_s_setprio(1); \
        _Pragma("unroll") \
        for (int ii = 0; ii < 4; ++ii) \
            _Pragma("unroll") \
            for (int ni = 0; ni < 3; ++ni) \
                acc[(MIB)+ii][ni] = MFMA_BF16(AARR[ii], BARR[ni], acc[(MIB)+ii][ni], 0, 0, 0); \
        __builtin_amdgcn_s_setprio(0);

    // prologue: tile 0 staged and certified
    issueT(0);
    asm volatile("s_waitcnt vmcnt(0)" ::: "memory");
    __builtin_amdgcn_s_barrier();
    __builtin_amdgcn_sched_barrier(0);

    for (int ks = 0; ks < NKS; ++ks) {
        const uint4* buf = smem + (ks & 1)*GRAN;
        bf16x8 a[4], a2[4], b[3];

        // ---- kk=0 ----
        #pragma unroll
        for (int mi = 0; mi < 4; ++mi) a[mi] = *(bf16x8*)&buf[ao[mi]];
        #pragma unroll
        for (int ni = 0; ni < 3; ++ni) b[ni] = *(bf16x8*)&buf[bo[ni]];
        if (ks + 1 < NKS) issueT(ks + 1);          // ~3/4-tile flight before certify
        #pragma unroll
        for (int mi = 0; mi < 4; ++mi) a2[mi] = *(bf16x8*)&buf[ao[4 + mi]];

        asm volatile("s_waitcnt lgkmcnt(4)" ::: "memory");   // a,b done
        __builtin_amdgcn_sched_barrier(0);
        MFMA12(a, 0, b)
        asm volatile("s_waitcnt lgkmcnt(0)" ::: "memory");   // a2 done
        __builtin_amdgcn_sched_barrier(0);
        MFMA12(a2, 4, b)

        // ---- kk=1 ----
        #pragma unroll
        for (int mi = 0; mi < 4; ++mi) a[mi] = *(bf16x8*)&buf[ao[mi] ^ 4];
        #pragma unroll
        for (int ni = 0; ni < 3; ++ni) b[ni] = *(bf16x8*)&buf[bo[ni] ^ 4];
        #pragma unroll
        for (int mi = 0; mi < 4; ++mi) a2[mi] = *(bf16x8*)&buf[ao[4 + mi] ^ 4];

        asm volatile("s_waitcnt lgkmcnt(4)" ::: "memory");
        __builtin_amdgcn_sched_barrier(0);
        MFMA12(a, 0, b)
        asm volatile("s_waitcnt lgkmcnt(0)" ::: "memory");
        __builtin_amdgcn_sched_barrier(0);
        MFMA12(a2, 4, b)

        // boundary: certify buf[(ks+1)&1] (stages landed long ago), one barrier
        if (ks + 1 < NKS) {
            asm volatile("s_waitcnt vmcnt(0)" ::: "memory");
            __builtin_amdgcn_s_barrier();
            __builtin_amdgcn_sched_barrier(0);
        }
    }

    __syncthreads();

    // --- epilogue: LDS restage [64][196] (2-way free), coalesced float4 stores ---
    float (*eps)[196] = (float (*)[196])smem;
    const int cl4 = (t % 48) * 4;                 // 0..188
    const int rsub = t / 48;                      // 0..7 for t<384
    const int colg = tile*BN + cl4;
    const int nn = colg / SPB;
    const int sp = colg - nn*SPB;                 // SPB%4==0 -> no straddle
    #pragma unroll
    for (int h = 0; h < 4; ++h) {
        if (wm == (h >> 1)) {
            const int mib = (h & 1) * 4;
            #pragma unroll
            for (int ii = 0; ii < 4; ++ii) {
                int rl = ii*16 + lq*4;
                #pragma unroll
                for (int ni = 0; ni < 3; ++ni) {
                    int cl = wn*48 + ni*16 + lr;
                    #pragma unroll
                    for (int r = 0; r < 4; ++r)
                        eps[rl + r][cl] = acc[mib + ii][ni][r];
                }
            }
        }
        __syncthreads();
        if (t < 384) {
            #pragma unroll
            for (int pass = 0; pass < 8; ++pass) {
                int rl = pass*8 + rsub;
                int rg = h*64 + rl;
                f32x4 v = *(f32x4*)&eps[rl][cl4];
                v = v + bias[rg];
                *(f32x4*)&out[((size_t)nn*OCH + rg)*SPB + sp] = v;
            }
        }
        __syncthreads();
    }
}

// ---- fallback: direct fp32 conv ----
__global__ void conv_naive(const float* __restrict__ x, const float* __restrict__ w,
                           const float* __restrict__ bias, float* __restrict__ out) {
    size_t tid = (size_t)blockIdx.x*256 + threadIdx.x;
    const size_t total = (size_t)NB*OCH*SPB;
    if (tid >= total) return;
    int col = (int)(tid % SPB);
    int oc  = (int)((tid / SPB) % OCH);
    int n   = (int)(tid / ((size_t)SPB*OCH));
    int oh = col / OHW, ow = col % OHW;
    float s = bias[oc];
    for (int ic = 0; ic < CIN; ++ic)
        #pragma unroll
        for (int kh = 0; kh < 3; ++kh)
            #pragma unroll
            for (int kw = 0; kw < 3; ++kw)
                s += x[((size_t)(n*CIN+ic)*HIN + oh+kh)*HIN + ow+kw]
                   * w[((size_t)(oc*CIN+ic)*3 + kh)*3 + kw];
    out[tid] = s;
}

extern "C" void kernel_launch(void* const* d_in, const int* in_sizes, int n_in,
                              void* d_out, int out_size, void* d_ws, size_t ws_size,
                              hipStream_t stream) {
    const float* x    = (const float*)d_in[0];
    const float* w    = (const float*)d_in[1];
    const float* bias = (const float*)d_in[2];
    float* out = (float*)d_out;

    const size_t xt_bytes = (size_t)NB*HW*CIN*sizeof(__hip_bfloat16);
    const size_t wt_bytes = (size_t)OCH*KSZ*sizeof(__hip_bfloat16);

    if (ws_size >= xt_bytes + wt_bytes) {
        __hip_bfloat16* xt  = (__hip_bfloat16*)d_ws;
        __hip_bfloat16* wtp = (__hip_bfloat16*)((char*)d_ws + xt_bytes);
        hipLaunchKernelGGL(prep, dim3(XPB + WCB), dim3(256), 0, stream, x, xt, w, wtp);
        hipLaunchKernelGGL(conv_mfma, dim3(NT), dim3(512), 0, stream, xt, wtp, bias, out);
    } else {
        size_t total = (size_t)NB*OCH*SPB;
        hipLaunchKernelGGL(conv_naive, dim3((unsigned)((total + 255)/256)), dim3(256), 0, stream,
                           x, w, bias, out);
    }
}